// Round 12
// baseline (217.164 us; speedup 1.0000x reference)
//
#include <hip/hip_runtime.h>
#include <hip/hip_bf16.h>
#include <stdint.h>

// OuterProductMean: b=1, m=256 (MSA), n=384 (seq), C=256, H=32, P=128.
//   prep_all: woT[p][cd'] bf16 (cd'=d*32+c); wg[c][k]=w[k][c]*ln_g[k] bf16,
//             Gc[c]=sum wg, B2[c]=sum w*ln_b + bias; inv_cnt mask GEMM.
//   ln_proj:  single-pass LN+proj, m-split x2 -> leftT/rightT [n*32+c][m] bf16
//   outer:    R11 sync skeleton (256x256 tile, 4 BK=64 steps, dbuf
//             global_load_lds, vmcnt(8), 2 barriers/step) with the K-step
//             region software-pipelined into 4 quadrant clusters: reads for
//             quadrant n+1 issue before quadrant n's MFMAs (lgkmcnt+sched_
//             barrier pinned). Epilogue = R11 verbatim (b64 A_ep writes,
//             bijective swizzle, p=wid*16+llo tiling, unroll 8).

typedef float f32x4 __attribute__((ext_vector_type(4)));
typedef __bf16 bf16x8 __attribute__((ext_vector_type(8)));
typedef __bf16 bf16x4 __attribute__((ext_vector_type(4)));

#define NSEQ 384
#define NMSA 256

typedef const __attribute__((address_space(1))) unsigned int* gptr_t;
typedef __attribute__((address_space(3))) unsigned int* lptr_t;

__device__ __forceinline__ void gload_lds16(const void* g, void* l) {
    __builtin_amdgcn_global_load_lds((gptr_t)g, (lptr_t)l, 16, 0, 0);
}

// ------------------------------------------------------------- prep_all ----
// blocks [0,512): woT (cd' reorder); [512,576): wg/Gc/B2; [576,960): cnt.
__global__ __launch_bounds__(256) void prep_all_kernel(
    const float* __restrict__ wo,
    const float* __restrict__ wl, const float* __restrict__ wr,
    const float* __restrict__ bl, const float* __restrict__ br,
    const float* __restrict__ ln_g, const float* __restrict__ ln_b,
    const int* __restrict__ mask,
    __bf16* __restrict__ woT, __bf16* __restrict__ wg,
    float* __restrict__ Gc, float* __restrict__ B2,
    float* __restrict__ inv_cnt)
{
    const int blk = blockIdx.x;
    __shared__ int mi[NMSA];
    __shared__ float sg[4], sb[4];

    if (blk < 512) {                           // woT[p*1024 + d*32 + c]
        int gid = blk * 256 + threadIdx.x;     // 131072 total
        int p = gid >> 10, q = gid & 1023;
        int d = q >> 5, c = q & 31;
        woT[gid] = (__bf16)wo[(c * 32 + d) * 128 + p];
    } else if (blk < 576) {                    // wg / Gc / B2
        const int c = blk - 512;               // 0..63
        const int k = threadIdx.x;             // 0..255
        float w = (c < 32) ? wl[k * 32 + c] : wr[k * 32 + (c - 32)];
        __bf16 wgb = (__bf16)(w * ln_g[k]);
        wg[c * 256 + k] = wgb;
        float gsum = (float)wgb;               // rounded so mu-term cancels
        float bsum = w * ln_b[k];
        for (int off = 32; off; off >>= 1) {
            gsum += __shfl_down(gsum, off);
            bsum += __shfl_down(bsum, off);
        }
        int wid = k >> 6, lane = k & 63;
        if (lane == 0) { sg[wid] = gsum; sb[wid] = bsum; }
        __syncthreads();
        if (k == 0) {
            Gc[c] = sg[0] + sg[1] + sg[2] + sg[3];
            B2[c] = sb[0] + sb[1] + sb[2] + sb[3] + ((c < 32) ? bl[c] : br[c - 32]);
        }
    } else {                                   // cnt
        const int i = blk - 576;
        const int t = threadIdx.x;
        mi[t] = mask[t * NSEQ + i];
        __syncthreads();
        for (int j = t; j < NSEQ; j += 256) {
            int acc = 0;
            for (int m = 0; m < NMSA; ++m)
                acc += mi[m] & mask[m * NSEQ + j];
            inv_cnt[i * NSEQ + j] = 1.0f / ((float)acc + 0.001f);
        }
    }
}

// ------------------------------------------------------------- ln_proj ----
__global__ __launch_bounds__(256) void ln_proj_kernel(
    const float* __restrict__ x, const int* __restrict__ mask,
    const __bf16* __restrict__ wg, const float* __restrict__ Gc,
    const float* __restrict__ B2,
    __bf16* __restrict__ leftT, __bf16* __restrict__ rightT)
{
    const int n = blockIdx.x % NSEQ;
    const int mh = blockIdx.x / NSEQ;          // 0..1
    const int m0 = mh * 128;
    const int tid = threadIdx.x;
    __shared__ __bf16 xnT[128 * 40];
    __shared__ float muS[128], rsS[128], maskS[128], GcS[64], B2S[64];

    if (tid < 64) { GcS[tid] = Gc[tid]; B2S[tid] = B2[tid]; }
    if (tid < 128) maskS[tid] = (float)mask[(m0 + tid) * NSEQ + n];

    const int wid = tid >> 6, lane = tid & 63;
    const int lhi = lane >> 4, llo = lane & 15;
    const int wrq = wid >> 1, wcq = wid & 1;   // 2x2 waves: c-half x m-half
    float ps[4] = {}, pq[4] = {};
    f32x4 acc[2][4] = {};

    for (int k0 = 0; k0 < 256; k0 += 32) {
        #pragma unroll
        for (int cc = 0; cc < 4; ++cc) {       // stage raw x [128 m][32 k] bf16
            int ch = tid + cc * 256;
            int mR = ch >> 3, c4 = ch & 7;
            f32x4 v = *reinterpret_cast<const f32x4*>(x + ((size_t)(m0 + mR) * NSEQ + n) * 256 + k0 + c4 * 4);
            ps[cc] += v[0] + v[1] + v[2] + v[3];
            pq[cc] += v[0]*v[0] + v[1]*v[1] + v[2]*v[2] + v[3]*v[3];
            __bf16* dst = xnT + mR * 40 + c4 * 4;
            dst[0] = (__bf16)v[0]; dst[1] = (__bf16)v[1];
            dst[2] = (__bf16)v[2]; dst[3] = (__bf16)v[3];
        }
        __syncthreads();
        bf16x8 af[2], bfr[4];
        #pragma unroll
        for (int fr = 0; fr < 2; ++fr)
            af[fr] = *reinterpret_cast<const bf16x8*>(wg + (size_t)(wrq * 32 + fr * 16 + llo) * 256 + k0 + lhi * 8);
        #pragma unroll
        for (int fc = 0; fc < 4; ++fc)
            bfr[fc] = *reinterpret_cast<const bf16x8*>(xnT + (wcq * 64 + fc * 16 + llo) * 40 + lhi * 8);
        #pragma unroll
        for (int fr = 0; fr < 2; ++fr)
            #pragma unroll
            for (int fc = 0; fc < 4; ++fc)
                acc[fr][fc] = __builtin_amdgcn_mfma_f32_16x16x32_bf16(af[fr], bfr[fc], acc[fr][fc], 0, 0, 0);
        __syncthreads();
    }

    #pragma unroll
    for (int cc = 0; cc < 4; ++cc) {
        float s = ps[cc], q = pq[cc];
        s += __shfl_xor(s, 1); q += __shfl_xor(q, 1);
        s += __shfl_xor(s, 2); q += __shfl_xor(q, 2);
        s += __shfl_xor(s, 4); q += __shfl_xor(q, 4);
        if ((tid & 7) == 0) {
            int mR = (tid >> 3) + cc * 32;
            float mu = s * (1.f / 256.f);
            float var = q * (1.f / 256.f) - mu * mu;
            muS[mR] = mu;
            rsS[mR] = rsqrtf(var + 1e-5f);
        }
    }
    __syncthreads();

    #pragma unroll
    for (int fr = 0; fr < 2; ++fr) {
        #pragma unroll
        for (int fc = 0; fc < 4; ++fc) {
            int mR = wcq * 64 + fc * 16 + llo;
            float mv = maskS[mR], rs = rsS[mR], mu = muS[mR];
            #pragma unroll
            for (int r = 0; r < 4; ++r) {
                int c = wrq * 32 + fr * 16 + lhi * 4 + r;
                float val = (acc[fr][fc][r] - mu * GcS[c]) * rs + B2S[c];
                __bf16 bv = (__bf16)(val * mv);
                if (c < 32) leftT [(size_t)(n * 32 + c)        * 256 + m0 + mR] = bv;
                else        rightT[(size_t)(n * 32 + (c - 32)) * 256 + m0 + mR] = bv;
            }
        }
    }
}

// --------------------------------------------------------------- outer ----
// R11 sync skeleton; K-step region pipelined into 4 quadrant clusters.
__global__ __launch_bounds__(512, 2) void outer_gemm_kernel(
    const __bf16* __restrict__ leftT, const __bf16* __restrict__ rightT,
    const __bf16* __restrict__ woT, const float* __restrict__ bo,
    const float* __restrict__ inv_cnt, float* __restrict__ out)
{
    __shared__ char smem[131072];
    const int tid = threadIdx.x;
    const int wid = tid >> 6, lane = tid & 63;
    const int lhi = lane >> 4, llo = lane & 15;
    const int wr = wid >> 2, wc = wid & 3;     // 2x4 wave grid, wave = 128x64

    int wg_ = blockIdx.x;
    int l  = (wg_ & 7) * 288 + (wg_ >> 3);     // XCD-chunked remap (2304 = 8*288)
    int bj = l / 48, bi = l % 48;

    char* Abuf[2] = { smem,         smem + 65536 };
    char* Bbuf[2] = { smem + 32768, smem + 98304 };

    auto STAGE = [&](int buf, int k0) {
        #pragma unroll
        for (int it = 0; it < 4; ++it) {
            int q = it * 512 + wid * 64 + lane;
            int r = q >> 3;
            int s = (q & 7) ^ (r & 7);
            int ldsoff = (it * 512 + wid * 64) * 16;        // wave-uniform
            gload_lds16(leftT  + (size_t)(bi * 256 + r) * 256 + k0 + s * 8, Abuf[buf] + ldsoff);
            gload_lds16(rightT + (size_t)(bj * 256 + r) * 256 + k0 + s * 8, Bbuf[buf] + ldsoff);
        }
    };

    f32x4 acc[8][4] = {};

    // fragment read helpers: row-swizzled b128 from current buffers
    #define ARD(FR, SB) (*(const bf16x8*)(Al + (wr * 128 + (FR) * 16 + llo) * 64 + \
                        (((SB) ^ ((wr * 128 + (FR) * 16 + llo) & 7)) << 3)))
    #define BRD(FC, SB) (*(const bf16x8*)(Bl + (wc * 64 + (FC) * 16 + llo) * 64 + \
                        (((SB) ^ ((wc * 64 + (FC) * 16 + llo) & 7)) << 3)))

    STAGE(0, 0);
    #pragma unroll
    for (int t = 0; t < 4; ++t) {
        if (t < 3) {
            STAGE((t + 1) & 1, (t + 1) * 64);
            asm volatile("s_waitcnt vmcnt(8)" ::: "memory");
        } else {
            asm volatile("s_waitcnt vmcnt(0)" ::: "memory");
        }
        __builtin_amdgcn_s_barrier();
        const __bf16* Al = (const __bf16*)Abuf[t & 1];
        const __bf16* Bl = (const __bf16*)Bbuf[t & 1];

        bf16x8 a0[4], a1[4], a2[4], a3[4];     // fr0-3 / fr4-7, kk0 / kk1
        bf16x8 b0[4], b1[4];                   // fc0-3, kk0 / kk1

        // R0: quadrant-0 operands (a fr0-3 both kk, b fc0-1 both kk)
        #pragma unroll
        for (int fr = 0; fr < 4; ++fr) { a0[fr] = ARD(fr, lhi); a1[fr] = ARD(fr, 4 + lhi); }
        #pragma unroll
        for (int fc = 0; fc < 2; ++fc) { b0[fc] = BRD(fc, lhi); b1[fc] = BRD(fc, 4 + lhi); }
        asm volatile("s_waitcnt lgkmcnt(0)" ::: "memory");
        __builtin_amdgcn_sched_barrier(0);

        // R1 issue (b fc2-3) under Q0 MFMAs
        #pragma unroll
        for (int fc = 2; fc < 4; ++fc) { b0[fc] = BRD(fc, lhi); b1[fc] = BRD(fc, 4 + lhi); }
        __builtin_amdgcn_s_setprio(1);
        #pragma unroll
        for (int fr = 0; fr < 4; ++fr)
            #pragma unroll
            for (int fc = 0; fc < 2; ++fc) {
                acc[fr][fc] = __builtin_amdgcn_mfma_f32_16x16x32_bf16(a0[fr], b0[fc], acc[fr][fc], 0, 0, 0);
                acc[fr][fc] = __builtin_amdgcn_mfma_f32_16x16x32_bf16(a1[fr], b1[fc], acc[fr][fc], 0, 0, 0);
            }
        __builtin_amdgcn_s_setprio(0);
        asm volatile("s_waitcnt lgkmcnt(0)" ::: "memory");
        __builtin_amdgcn_sched_barrier(0);

        // R2 issue (a fr4-7) under Q1 MFMAs
        #pragma unroll
        for (int fr = 0; fr < 4; ++fr) { a2[fr] = ARD(fr + 4, lhi); a3[fr] = ARD(fr + 4, 4 + lhi); }
        __builtin_amdgcn_s_setprio(1);
        #pragma unroll
        for (int fr = 0; fr < 4; ++fr)
            #pragma unroll
            for (int fc = 2; fc < 4; ++fc) {
                acc[fr][fc] = __builtin_amdgcn_mfma_f32_16x16x32_bf16(a0[fr], b0[fc], acc[fr][fc], 0, 0, 0);
                acc[fr][fc] = __builtin_amdgcn_mfma_f32_16x16x32_bf16(a1[fr], b1[fc], acc[fr][fc], 0, 0, 0);
            }
        __builtin_amdgcn_s_setprio(0);
        asm volatile("s_waitcnt lgkmcnt(0)" ::: "memory");
        __builtin_amdgcn_sched_barrier(0);

        // Q2 + Q3 (all operands in regs)
        __builtin_amdgcn_s_setprio(1);
        #pragma unroll
        for (int fr = 0; fr < 4; ++fr)
            #pragma unroll
            for (int fc = 0; fc < 4; ++fc) {
                acc[fr + 4][fc] = __builtin_amdgcn_mfma_f32_16x16x32_bf16(a2[fr], b0[fc], acc[fr + 4][fc], 0, 0, 0);
                acc[fr + 4][fc] = __builtin_amdgcn_mfma_f32_16x16x32_bf16(a3[fr], b1[fc], acc[fr + 4][fc], 0, 0, 0);
            }
        __builtin_amdgcn_s_setprio(0);
        __builtin_amdgcn_s_barrier();          // trailing (reads already drained)
    }
    #undef ARD
    #undef BRD

    // ---- O-tile -> A_ep[64 ij][1024 cd'] bf16, b64 writes, pi-swizzle ----
    // cd' = d*32+c; ij = (gi>>5)*8 + (gj>>5); t = cd'>>3;
    // phys = ((t&3)<<5 | (t>>2)) ^ (ij&15)   [bijective; 2-way max]
    __bf16* Aep = (__bf16*)smem;
    #pragma unroll
    for (int fr = 0; fr < 8; ++fr) {
        #pragma unroll
        for (int fc = 0; fc < 4; ++fc) {
            int ij = (wr * 4 + (fr >> 1)) * 8 + wc * 2 + (fc >> 1);
            int t = ((fc & 1) * 16 + llo) * 4 + (fr & 1) * 2 + (lhi >> 1);
            int phys = (((t & 3) << 5) | (t >> 2)) ^ (ij & 15);
            bf16x4 v;
            v[0] = (__bf16)acc[fr][fc][0]; v[1] = (__bf16)acc[fr][fc][1];
            v[2] = (__bf16)acc[fr][fc][2]; v[3] = (__bf16)acc[fr][fc][3];
            *(bf16x4*)(Aep + ij * 1024 + (phys << 3) + (lhi & 1) * 4) = v;
        }
    }
    __syncthreads();

    // ---- epilogue GEMM (R11): wave owns p = wid*16+llo, mf = 4 ----
    f32x4 eacc[4] = {};
    const int p = wid * 16 + llo;
    const __bf16* wrow = woT + (size_t)p * 1024 + lhi * 8;
    #pragma unroll 8
    for (int k0 = 0; k0 < 1024; k0 += 32) {
        bf16x8 bw = *(const bf16x8*)(wrow + k0);
        int base = (lhi << 5) | (k0 >> 5);
        #pragma unroll
        for (int mf = 0; mf < 4; ++mf) {
            int ij = mf * 16 + llo;            // ij & 15 == llo
            int phys = base ^ llo;
            bf16x8 a = *(const bf16x8*)(Aep + ij * 1024 + (phys << 3));
            eacc[mf] = __builtin_amdgcn_mfma_f32_16x16x32_bf16(a, bw, eacc[mf], 0, 0, 0);
        }
    }

    const float bov = bo[p];
    #pragma unroll
    for (int mf = 0; mf < 4; ++mf) {
        #pragma unroll
        for (int r = 0; r < 4; ++r) {
            int ij = mf * 16 + lhi * 4 + r;
            int i = bi * 8 + (ij >> 3);
            int j = bj * 8 + (ij & 7);
            size_t idx = (size_t)i * NSEQ + j;
            out[idx * 128 + p] = (eacc[mf][r] + bov) * inv_cnt[idx];
        }
    }
}

// -------------------------------------------------------------- launch ----
extern "C" void kernel_launch(void* const* d_in, const int* in_sizes, int n_in,
                              void* d_out, int out_size, void* d_ws, size_t ws_size,
                              hipStream_t stream) {
    const float* x    = (const float*)d_in[0];
    const int*   mask = (const int*)  d_in[1];
    const float* ln_g = (const float*)d_in[2];
    const float* ln_b = (const float*)d_in[3];
    const float* wl   = (const float*)d_in[4];
    const float* bl   = (const float*)d_in[5];
    const float* wr   = (const float*)d_in[6];
    const float* br   = (const float*)d_in[7];
    const float* wo   = (const float*)d_in[8];
    const float* bo   = (const float*)d_in[9];
    float* out = (float*)d_out;

    char* ws = (char*)d_ws;
    __bf16* leftT   = (__bf16*)(ws);             // 6,291,456
    __bf16* rightT  = (__bf16*)(ws + 6291456);   // 6,291,456
    __bf16* woT     = (__bf16*)(ws + 12582912);  // 262,144
    __bf16* wg      = (__bf16*)(ws + 12845056);  // 32,768
    float*  Gc      = (float*) (ws + 12877824);  // 256
    float*  B2      = (float*) (ws + 12878080);  // 256
    float*  inv_cnt = (float*) (ws + 12878336);  // 589,824 (end ~13.5 MB)

    prep_all_kernel<<<960, 256, 0, stream>>>(wo, wl, wr, bl, br, ln_g, ln_b, mask,
                                             woT, wg, Gc, B2, inv_cnt);
    ln_proj_kernel<<<768, 256, 0, stream>>>(x, mask, wg, Gc, B2, leftT, rightT);
    outer_gemm_kernel<<<2304, 512, 0, stream>>>(leftT, rightT, woT, bo, inv_cnt, out);
}

// Round 13
// 199.039 us; speedup vs baseline: 1.0911x; 1.0911x over previous
//
#include <hip/hip_runtime.h>
#include <hip/hip_bf16.h>
#include <stdint.h>

// OuterProductMean: b=1, m=256 (MSA), n=384 (seq), C=256, H=32, P=128.
//   prep_all: woT[p][cd'] bf16 (cd'=d*32+c); wg[c][k]=w[k][c]*ln_g[k] bf16,
//             Gc[c]=sum wg, B2[c]=sum w*ln_b + bias; inv_cnt mask GEMM.
//   ln_proj:  single-pass LN+proj, m-split x2 -> leftT/rightT [n*32+c][m] bf16
//   outer:    R11 skeleton (256x256 tile, 4 BK=64 steps, dbuf global_load_lds,
//             vmcnt(8), 2 regions/step of {12 ds_read -> lgkm -> MFMA cluster})
//             with the main-loop MFMA switched to 32x32x16 (1.20x pipe rate,
//             half the instructions). A_ep mapping identical to R11 (phys =
//             ((t&3)<<5 | t>>2) ^ (ij&15)); epilogue verbatim R11.

typedef float f32x4 __attribute__((ext_vector_type(4)));
typedef float f32x16 __attribute__((ext_vector_type(16)));
typedef __bf16 bf16x8 __attribute__((ext_vector_type(8)));
typedef __bf16 bf16x4 __attribute__((ext_vector_type(4)));

#define NSEQ 384
#define NMSA 256

typedef const __attribute__((address_space(1))) unsigned int* gptr_t;
typedef __attribute__((address_space(3))) unsigned int* lptr_t;

__device__ __forceinline__ void gload_lds16(const void* g, void* l) {
    __builtin_amdgcn_global_load_lds((gptr_t)g, (lptr_t)l, 16, 0, 0);
}

// ------------------------------------------------------------- prep_all ----
// blocks [0,512): woT (cd' reorder); [512,576): wg/Gc/B2; [576,960): cnt.
__global__ __launch_bounds__(256) void prep_all_kernel(
    const float* __restrict__ wo,
    const float* __restrict__ wl, const float* __restrict__ wr,
    const float* __restrict__ bl, const float* __restrict__ br,
    const float* __restrict__ ln_g, const float* __restrict__ ln_b,
    const int* __restrict__ mask,
    __bf16* __restrict__ woT, __bf16* __restrict__ wg,
    float* __restrict__ Gc, float* __restrict__ B2,
    float* __restrict__ inv_cnt)
{
    const int blk = blockIdx.x;
    __shared__ int mi[NMSA];
    __shared__ float sg[4], sb[4];

    if (blk < 512) {                           // woT[p*1024 + d*32 + c]
        int gid = blk * 256 + threadIdx.x;     // 131072 total
        int p = gid >> 10, q = gid & 1023;
        int d = q >> 5, c = q & 31;
        woT[gid] = (__bf16)wo[(c * 32 + d) * 128 + p];
    } else if (blk < 576) {                    // wg / Gc / B2
        const int c = blk - 512;               // 0..63
        const int k = threadIdx.x;             // 0..255
        float w = (c < 32) ? wl[k * 32 + c] : wr[k * 32 + (c - 32)];
        __bf16 wgb = (__bf16)(w * ln_g[k]);
        wg[c * 256 + k] = wgb;
        float gsum = (float)wgb;               // rounded so mu-term cancels
        float bsum = w * ln_b[k];
        for (int off = 32; off; off >>= 1) {
            gsum += __shfl_down(gsum, off);
            bsum += __shfl_down(bsum, off);
        }
        int wid = k >> 6, lane = k & 63;
        if (lane == 0) { sg[wid] = gsum; sb[wid] = bsum; }
        __syncthreads();
        if (k == 0) {
            Gc[c] = sg[0] + sg[1] + sg[2] + sg[3];
            B2[c] = sb[0] + sb[1] + sb[2] + sb[3] + ((c < 32) ? bl[c] : br[c - 32]);
        }
    } else {                                   // cnt
        const int i = blk - 576;
        const int t = threadIdx.x;
        mi[t] = mask[t * NSEQ + i];
        __syncthreads();
        for (int j = t; j < NSEQ; j += 256) {
            int acc = 0;
            for (int m = 0; m < NMSA; ++m)
                acc += mi[m] & mask[m * NSEQ + j];
            inv_cnt[i * NSEQ + j] = 1.0f / ((float)acc + 0.001f);
        }
    }
}

// ------------------------------------------------------------- ln_proj ----
__global__ __launch_bounds__(256) void ln_proj_kernel(
    const float* __restrict__ x, const int* __restrict__ mask,
    const __bf16* __restrict__ wg, const float* __restrict__ Gc,
    const float* __restrict__ B2,
    __bf16* __restrict__ leftT, __bf16* __restrict__ rightT)
{
    const int n = blockIdx.x % NSEQ;
    const int mh = blockIdx.x / NSEQ;          // 0..1
    const int m0 = mh * 128;
    const int tid = threadIdx.x;
    __shared__ __bf16 xnT[128 * 40];
    __shared__ float muS[128], rsS[128], maskS[128], GcS[64], B2S[64];

    if (tid < 64) { GcS[tid] = Gc[tid]; B2S[tid] = B2[tid]; }
    if (tid < 128) maskS[tid] = (float)mask[(m0 + tid) * NSEQ + n];

    const int wid = tid >> 6, lane = tid & 63;
    const int lhi = lane >> 4, llo = lane & 15;
    const int wrq = wid >> 1, wcq = wid & 1;   // 2x2 waves: c-half x m-half
    float ps[4] = {}, pq[4] = {};
    f32x4 acc[2][4] = {};

    for (int k0 = 0; k0 < 256; k0 += 32) {
        #pragma unroll
        for (int cc = 0; cc < 4; ++cc) {       // stage raw x [128 m][32 k] bf16
            int ch = tid + cc * 256;
            int mR = ch >> 3, c4 = ch & 7;
            f32x4 v = *reinterpret_cast<const f32x4*>(x + ((size_t)(m0 + mR) * NSEQ + n) * 256 + k0 + c4 * 4);
            ps[cc] += v[0] + v[1] + v[2] + v[3];
            pq[cc] += v[0]*v[0] + v[1]*v[1] + v[2]*v[2] + v[3]*v[3];
            __bf16* dst = xnT + mR * 40 + c4 * 4;
            dst[0] = (__bf16)v[0]; dst[1] = (__bf16)v[1];
            dst[2] = (__bf16)v[2]; dst[3] = (__bf16)v[3];
        }
        __syncthreads();
        bf16x8 af[2], bfr[4];
        #pragma unroll
        for (int fr = 0; fr < 2; ++fr)
            af[fr] = *reinterpret_cast<const bf16x8*>(wg + (size_t)(wrq * 32 + fr * 16 + llo) * 256 + k0 + lhi * 8);
        #pragma unroll
        for (int fc = 0; fc < 4; ++fc)
            bfr[fc] = *reinterpret_cast<const bf16x8*>(xnT + (wcq * 64 + fc * 16 + llo) * 40 + lhi * 8);
        #pragma unroll
        for (int fr = 0; fr < 2; ++fr)
            #pragma unroll
            for (int fc = 0; fc < 4; ++fc)
                acc[fr][fc] = __builtin_amdgcn_mfma_f32_16x16x32_bf16(af[fr], bfr[fc], acc[fr][fc], 0, 0, 0);
        __syncthreads();
    }

    #pragma unroll
    for (int cc = 0; cc < 4; ++cc) {
        float s = ps[cc], q = pq[cc];
        s += __shfl_xor(s, 1); q += __shfl_xor(q, 1);
        s += __shfl_xor(s, 2); q += __shfl_xor(q, 2);
        s += __shfl_xor(s, 4); q += __shfl_xor(q, 4);
        if ((tid & 7) == 0) {
            int mR = (tid >> 3) + cc * 32;
            float mu = s * (1.f / 256.f);
            float var = q * (1.f / 256.f) - mu * mu;
            muS[mR] = mu;
            rsS[mR] = rsqrtf(var + 1e-5f);
        }
    }
    __syncthreads();

    #pragma unroll
    for (int fr = 0; fr < 2; ++fr) {
        #pragma unroll
        for (int fc = 0; fc < 4; ++fc) {
            int mR = wcq * 64 + fc * 16 + llo;
            float mv = maskS[mR], rs = rsS[mR], mu = muS[mR];
            #pragma unroll
            for (int r = 0; r < 4; ++r) {
                int c = wrq * 32 + fr * 16 + lhi * 4 + r;
                float val = (acc[fr][fc][r] - mu * GcS[c]) * rs + B2S[c];
                __bf16 bv = (__bf16)(val * mv);
                if (c < 32) leftT [(size_t)(n * 32 + c)        * 256 + m0 + mR] = bv;
                else        rightT[(size_t)(n * 32 + (c - 32)) * 256 + m0 + mR] = bv;
            }
        }
    }
}

// --------------------------------------------------------------- outer ----
// R11 skeleton; main loop on mfma_f32_32x32x16_bf16.
// Wave tile 128x64 = 4x2 tiles of 32x32; acc = 8 x f32x16 (128 AGPR).
__global__ __launch_bounds__(512, 2) void outer_gemm_kernel(
    const __bf16* __restrict__ leftT, const __bf16* __restrict__ rightT,
    const __bf16* __restrict__ woT, const float* __restrict__ bo,
    const float* __restrict__ inv_cnt, float* __restrict__ out)
{
    __shared__ char smem[131072];
    const int tid = threadIdx.x;
    const int wid = tid >> 6, lane = tid & 63;
    const int lhi = lane >> 4, llo = lane & 15;
    const int l31 = lane & 31, l5 = lane >> 5;
    const int wr = wid >> 2, wc = wid & 3;     // 2x4 wave grid, wave = 128x64

    int wg_ = blockIdx.x;
    int l  = (wg_ & 7) * 288 + (wg_ >> 3);     // XCD-chunked remap (2304 = 8*288)
    int bj = l / 48, bi = l % 48;

    char* Abuf[2] = { smem,         smem + 65536 };
    char* Bbuf[2] = { smem + 32768, smem + 98304 };

    auto STAGE = [&](int buf, int k0) {
        #pragma unroll
        for (int it = 0; it < 4; ++it) {
            int q = it * 512 + wid * 64 + lane;
            int r = q >> 3;
            int s = (q & 7) ^ (r & 7);
            int ldsoff = (it * 512 + wid * 64) * 16;        // wave-uniform
            gload_lds16(leftT  + (size_t)(bi * 256 + r) * 256 + k0 + s * 8, Abuf[buf] + ldsoff);
            gload_lds16(rightT + (size_t)(bj * 256 + r) * 256 + k0 + s * 8, Bbuf[buf] + ldsoff);
        }
    };

    f32x16 acc[4][2] = {};

    // A fragment (32x32x16): row = wr*128 + rt*32 + l31, k-slot = kc*2 + l5
    #define ARD32(RT, KC) (*(const bf16x8*)(Al + (wr * 128 + (RT) * 32 + l31) * 64 + \
                          ((((KC) * 2 + l5) ^ ((wr * 128 + (RT) * 32 + l31) & 7)) << 3)))
    #define BRD32(CT, KC) (*(const bf16x8*)(Bl + (wc * 64 + (CT) * 32 + l31) * 64 + \
                          ((((KC) * 2 + l5) ^ ((wc * 64 + (CT) * 32 + l31) & 7)) << 3)))

    STAGE(0, 0);
    #pragma unroll
    for (int t = 0; t < 4; ++t) {
        if (t < 3) {
            STAGE((t + 1) & 1, (t + 1) * 64);
            asm volatile("s_waitcnt vmcnt(8)" ::: "memory");
        } else {
            asm volatile("s_waitcnt vmcnt(0)" ::: "memory");
        }
        __builtin_amdgcn_s_barrier();
        const __bf16* Al = (const __bf16*)Abuf[t & 1];
        const __bf16* Bl = (const __bf16*)Bbuf[t & 1];
        #pragma unroll
        for (int half = 0; half < 2; ++half) { // kc pair {0,1} / {2,3}
            const int kc0 = half * 2;
            bf16x8 a0[4], a1[4], b0[2], b1[2];
            #pragma unroll
            for (int rt = 0; rt < 4; ++rt) { a0[rt] = ARD32(rt, kc0); a1[rt] = ARD32(rt, kc0 + 1); }
            #pragma unroll
            for (int ct = 0; ct < 2; ++ct) { b0[ct] = BRD32(ct, kc0); b1[ct] = BRD32(ct, kc0 + 1); }
            asm volatile("s_waitcnt lgkmcnt(0)" ::: "memory");
            __builtin_amdgcn_sched_barrier(0);
            __builtin_amdgcn_s_setprio(1);
            #pragma unroll
            for (int rt = 0; rt < 4; ++rt)
                #pragma unroll
                for (int ct = 0; ct < 2; ++ct) {
                    acc[rt][ct] = __builtin_amdgcn_mfma_f32_32x32x16_bf16(a0[rt], b0[ct], acc[rt][ct], 0, 0, 0);
                    acc[rt][ct] = __builtin_amdgcn_mfma_f32_32x32x16_bf16(a1[rt], b1[ct], acc[rt][ct], 0, 0, 0);
                }
            __builtin_amdgcn_s_setprio(0);
            __builtin_amdgcn_s_barrier();      // mid (half=0) / trailing (half=1)
        }
    }
    #undef ARD32
    #undef BRD32

    // ---- O-tile -> A_ep[64 ij][1024 cd'] bf16, b64 writes ----
    // 32x32 D layout (m74/m101): col d = lane&31, row c = (reg&3)+8*(reg>>2)+4*l5.
    // cd' = d*32+c; t = cd'>>3 = d*4 + (reg>>2); phys = ((t&3)<<5 | t>>2) ^ (ij&15)
    //             = ((reg>>2)<<5 | d) ^ (ij&15)   [same mapping as R11]
    __bf16* Aep = (__bf16*)smem;
    #pragma unroll
    for (int rt = 0; rt < 4; ++rt) {
        #pragma unroll
        for (int ct = 0; ct < 2; ++ct) {
            int ij = (wr * 4 + rt) * 8 + wc * 2 + ct;
            #pragma unroll
            for (int q = 0; q < 4; ++q) {
                int phys = ((q << 5) | l31) ^ (ij & 15);
                bf16x4 v;
                v[0] = (__bf16)acc[rt][ct][q * 4 + 0];
                v[1] = (__bf16)acc[rt][ct][q * 4 + 1];
                v[2] = (__bf16)acc[rt][ct][q * 4 + 2];
                v[3] = (__bf16)acc[rt][ct][q * 4 + 3];
                *(bf16x4*)(Aep + ij * 1024 + phys * 8 + l5 * 4) = v;
            }
        }
    }
    __syncthreads();

    // ---- epilogue GEMM (R11 verbatim): wave owns p = wid*16+llo, mf = 4 ----
    f32x4 eacc[4] = {};
    const int p = wid * 16 + llo;
    const __bf16* wrow = woT + (size_t)p * 1024 + lhi * 8;
    #pragma unroll 8
    for (int k0 = 0; k0 < 1024; k0 += 32) {
        bf16x8 bw = *(const bf16x8*)(wrow + k0);
        int base = (lhi << 5) | (k0 >> 5);
        #pragma unroll
        for (int mf = 0; mf < 4; ++mf) {
            int ij = mf * 16 + llo;            // ij & 15 == llo
            int phys = base ^ llo;
            bf16x8 a = *(const bf16x8*)(Aep + ij * 1024 + (phys << 3));
            eacc[mf] = __builtin_amdgcn_mfma_f32_16x16x32_bf16(a, bw, eacc[mf], 0, 0, 0);
        }
    }

    const float bov = bo[p];
    #pragma unroll
    for (int mf = 0; mf < 4; ++mf) {
        #pragma unroll
        for (int r = 0; r < 4; ++r) {
            int ij = mf * 16 + lhi * 4 + r;
            int i = bi * 8 + (ij >> 3);
            int j = bj * 8 + (ij & 7);
            size_t idx = (size_t)i * NSEQ + j;
            out[idx * 128 + p] = (eacc[mf][r] + bov) * inv_cnt[idx];
        }
    }
}

// -------------------------------------------------------------- launch ----
extern "C" void kernel_launch(void* const* d_in, const int* in_sizes, int n_in,
                              void* d_out, int out_size, void* d_ws, size_t ws_size,
                              hipStream_t stream) {
    const float* x    = (const float*)d_in[0];
    const int*   mask = (const int*)  d_in[1];
    const float* ln_g = (const float*)d_in[2];
    const float* ln_b = (const float*)d_in[3];
    const float* wl   = (const float*)d_in[4];
    const float* bl   = (const float*)d_in[5];
    const float* wr   = (const float*)d_in[6];
    const float* br   = (const float*)d_in[7];
    const float* wo   = (const float*)d_in[8];
    const float* bo   = (const float*)d_in[9];
    float* out = (float*)d_out;

    char* ws = (char*)d_ws;
    __bf16* leftT   = (__bf16*)(ws);             // 6,291,456
    __bf16* rightT  = (__bf16*)(ws + 6291456);   // 6,291,456
    __bf16* woT     = (__bf16*)(ws + 12582912);  // 262,144
    __bf16* wg      = (__bf16*)(ws + 12845056);  // 32,768
    float*  Gc      = (float*) (ws + 12877824);  // 256
    float*  B2      = (float*) (ws + 12878080);  // 256
    float*  inv_cnt = (float*) (ws + 12878336);  // 589,824 (end ~13.5 MB)

    prep_all_kernel<<<960, 256, 0, stream>>>(wo, wl, wr, bl, br, ln_g, ln_b, mask,
                                             woT, wg, Gc, B2, inv_cnt);
    ln_proj_kernel<<<768, 256, 0, stream>>>(x, mask, wg, Gc, B2, leftT, rightT);
    outer_gemm_kernel<<<2304, 512, 0, stream>>>(leftT, rightT, woT, bo, inv_cnt, out);
}

// Round 14
// 187.727 us; speedup vs baseline: 1.1568x; 1.0603x over previous
//
#include <hip/hip_runtime.h>
#include <hip/hip_bf16.h>
#include <stdint.h>

// OuterProductMean: b=1, m=256 (MSA), n=384 (seq), C=256, H=32, P=128.
//   prep_all: woT[p][cd'] bf16 (cd'=d*32+c); wg[c][k]=w[k][c]*ln_g[k] bf16,
//             Gc[c]=sum wg, B2[c]=sum w*ln_b + bias; inv_cnt mask GEMM.
//   ln_proj:  single-pass LN+proj, m-split x2 -> leftT/rightT [n*32+c][m] bf16
//   outer:    R11 kernel verbatim (champion: 256x256 tile, 16x16x32 main loop,
//             dbuf global_load_lds + vmcnt(8), b64 A_ep writes w/ bijective
//             swizzle, p=wid*16+llo epilogue) EXCEPT the block remap: within
//             each XCD, blocks ordered as 6 bi-groups(8) x 6 bj x 8 bi so the
//             concurrent L2 working set is ~1.8MB (< 4MB/XCD) -> staging hits L2.

typedef float f32x4 __attribute__((ext_vector_type(4)));
typedef __bf16 bf16x8 __attribute__((ext_vector_type(8)));
typedef __bf16 bf16x4 __attribute__((ext_vector_type(4)));

#define NSEQ 384
#define NMSA 256

typedef const __attribute__((address_space(1))) unsigned int* gptr_t;
typedef __attribute__((address_space(3))) unsigned int* lptr_t;

__device__ __forceinline__ void gload_lds16(const void* g, void* l) {
    __builtin_amdgcn_global_load_lds((gptr_t)g, (lptr_t)l, 16, 0, 0);
}

// ------------------------------------------------------------- prep_all ----
// blocks [0,512): woT (cd' reorder); [512,576): wg/Gc/B2; [576,960): cnt.
__global__ __launch_bounds__(256) void prep_all_kernel(
    const float* __restrict__ wo,
    const float* __restrict__ wl, const float* __restrict__ wr,
    const float* __restrict__ bl, const float* __restrict__ br,
    const float* __restrict__ ln_g, const float* __restrict__ ln_b,
    const int* __restrict__ mask,
    __bf16* __restrict__ woT, __bf16* __restrict__ wg,
    float* __restrict__ Gc, float* __restrict__ B2,
    float* __restrict__ inv_cnt)
{
    const int blk = blockIdx.x;
    __shared__ int mi[NMSA];
    __shared__ float sg[4], sb[4];

    if (blk < 512) {                           // woT[p*1024 + d*32 + c]
        int gid = blk * 256 + threadIdx.x;     // 131072 total
        int p = gid >> 10, q = gid & 1023;
        int d = q >> 5, c = q & 31;
        woT[gid] = (__bf16)wo[(c * 32 + d) * 128 + p];
    } else if (blk < 576) {                    // wg / Gc / B2
        const int c = blk - 512;               // 0..63
        const int k = threadIdx.x;             // 0..255
        float w = (c < 32) ? wl[k * 32 + c] : wr[k * 32 + (c - 32)];
        __bf16 wgb = (__bf16)(w * ln_g[k]);
        wg[c * 256 + k] = wgb;
        float gsum = (float)wgb;               // rounded so mu-term cancels
        float bsum = w * ln_b[k];
        for (int off = 32; off; off >>= 1) {
            gsum += __shfl_down(gsum, off);
            bsum += __shfl_down(bsum, off);
        }
        int wid = k >> 6, lane = k & 63;
        if (lane == 0) { sg[wid] = gsum; sb[wid] = bsum; }
        __syncthreads();
        if (k == 0) {
            Gc[c] = sg[0] + sg[1] + sg[2] + sg[3];
            B2[c] = sb[0] + sb[1] + sb[2] + sb[3] + ((c < 32) ? bl[c] : br[c - 32]);
        }
    } else {                                   // cnt
        const int i = blk - 576;
        const int t = threadIdx.x;
        mi[t] = mask[t * NSEQ + i];
        __syncthreads();
        for (int j = t; j < NSEQ; j += 256) {
            int acc = 0;
            for (int m = 0; m < NMSA; ++m)
                acc += mi[m] & mask[m * NSEQ + j];
            inv_cnt[i * NSEQ + j] = 1.0f / ((float)acc + 0.001f);
        }
    }
}

// ------------------------------------------------------------- ln_proj ----
__global__ __launch_bounds__(256) void ln_proj_kernel(
    const float* __restrict__ x, const int* __restrict__ mask,
    const __bf16* __restrict__ wg, const float* __restrict__ Gc,
    const float* __restrict__ B2,
    __bf16* __restrict__ leftT, __bf16* __restrict__ rightT)
{
    const int n = blockIdx.x % NSEQ;
    const int mh = blockIdx.x / NSEQ;          // 0..1
    const int m0 = mh * 128;
    const int tid = threadIdx.x;
    __shared__ __bf16 xnT[128 * 40];
    __shared__ float muS[128], rsS[128], maskS[128], GcS[64], B2S[64];

    if (tid < 64) { GcS[tid] = Gc[tid]; B2S[tid] = B2[tid]; }
    if (tid < 128) maskS[tid] = (float)mask[(m0 + tid) * NSEQ + n];

    const int wid = tid >> 6, lane = tid & 63;
    const int lhi = lane >> 4, llo = lane & 15;
    const int wrq = wid >> 1, wcq = wid & 1;   // 2x2 waves: c-half x m-half
    float ps[4] = {}, pq[4] = {};
    f32x4 acc[2][4] = {};

    for (int k0 = 0; k0 < 256; k0 += 32) {
        #pragma unroll
        for (int cc = 0; cc < 4; ++cc) {       // stage raw x [128 m][32 k] bf16
            int ch = tid + cc * 256;
            int mR = ch >> 3, c4 = ch & 7;
            f32x4 v = *reinterpret_cast<const f32x4*>(x + ((size_t)(m0 + mR) * NSEQ + n) * 256 + k0 + c4 * 4);
            ps[cc] += v[0] + v[1] + v[2] + v[3];
            pq[cc] += v[0]*v[0] + v[1]*v[1] + v[2]*v[2] + v[3]*v[3];
            __bf16* dst = xnT + mR * 40 + c4 * 4;
            dst[0] = (__bf16)v[0]; dst[1] = (__bf16)v[1];
            dst[2] = (__bf16)v[2]; dst[3] = (__bf16)v[3];
        }
        __syncthreads();
        bf16x8 af[2], bfr[4];
        #pragma unroll
        for (int fr = 0; fr < 2; ++fr)
            af[fr] = *reinterpret_cast<const bf16x8*>(wg + (size_t)(wrq * 32 + fr * 16 + llo) * 256 + k0 + lhi * 8);
        #pragma unroll
        for (int fc = 0; fc < 4; ++fc)
            bfr[fc] = *reinterpret_cast<const bf16x8*>(xnT + (wcq * 64 + fc * 16 + llo) * 40 + lhi * 8);
        #pragma unroll
        for (int fr = 0; fr < 2; ++fr)
            #pragma unroll
            for (int fc = 0; fc < 4; ++fc)
                acc[fr][fc] = __builtin_amdgcn_mfma_f32_16x16x32_bf16(af[fr], bfr[fc], acc[fr][fc], 0, 0, 0);
        __syncthreads();
    }

    #pragma unroll
    for (int cc = 0; cc < 4; ++cc) {
        float s = ps[cc], q = pq[cc];
        s += __shfl_xor(s, 1); q += __shfl_xor(q, 1);
        s += __shfl_xor(s, 2); q += __shfl_xor(q, 2);
        s += __shfl_xor(s, 4); q += __shfl_xor(q, 4);
        if ((tid & 7) == 0) {
            int mR = (tid >> 3) + cc * 32;
            float mu = s * (1.f / 256.f);
            float var = q * (1.f / 256.f) - mu * mu;
            muS[mR] = mu;
            rsS[mR] = rsqrtf(var + 1e-5f);
        }
    }
    __syncthreads();

    #pragma unroll
    for (int fr = 0; fr < 2; ++fr) {
        #pragma unroll
        for (int fc = 0; fc < 4; ++fc) {
            int mR = wcq * 64 + fc * 16 + llo;
            float mv = maskS[mR], rs = rsS[mR], mu = muS[mR];
            #pragma unroll
            for (int r = 0; r < 4; ++r) {
                int c = wrq * 32 + fr * 16 + lhi * 4 + r;
                float val = (acc[fr][fc][r] - mu * GcS[c]) * rs + B2S[c];
                __bf16 bv = (__bf16)(val * mv);
                if (c < 32) leftT [(size_t)(n * 32 + c)        * 256 + m0 + mR] = bv;
                else        rightT[(size_t)(n * 32 + (c - 32)) * 256 + m0 + mR] = bv;
            }
        }
    }
}

// --------------------------------------------------------------- outer ----
// R11 verbatim except the block remap (L2-tiled within XCD).
__global__ __launch_bounds__(512, 2) void outer_gemm_kernel(
    const __bf16* __restrict__ leftT, const __bf16* __restrict__ rightT,
    const __bf16* __restrict__ woT, const float* __restrict__ bo,
    const float* __restrict__ inv_cnt, float* __restrict__ out)
{
    __shared__ char smem[131072];
    const int tid = threadIdx.x;
    const int wid = tid >> 6, lane = tid & 63;
    const int lhi = lane >> 4, llo = lane & 15;
    const int wr = wid >> 2, wc = wid & 3;     // 2x4 wave grid, wave = 128x64

    // L2-tiled XCD remap: XCD owns bj in [xcd*6, xcd*6+6); its 288 blocks
    // ordered as {bi-group of 8} x {6 bj} x {8 bi} -> concurrent working set
    // ~8 A-panels + <=6 B-panels ~= 1.8MB < 4MB L2 per XCD.  (bijective)
    int wg_ = blockIdx.x;
    int xcd = wg_ & 7;
    int g   = wg_ >> 3;                        // 0..287
    int big = g / 48;                          // 0..5
    int rem = g - big * 48;
    int bjx = rem >> 3;                        // 0..5
    int bii = rem & 7;                         // 0..7
    int bi  = big * 8 + bii;                   // 0..47
    int bj  = xcd * 6 + bjx;                   // 0..47

    char* Abuf[2] = { smem,         smem + 65536 };
    char* Bbuf[2] = { smem + 32768, smem + 98304 };

    auto STAGE = [&](int buf, int k0) {
        #pragma unroll
        for (int it = 0; it < 4; ++it) {
            int q = it * 512 + wid * 64 + lane;
            int r = q >> 3;
            int s = (q & 7) ^ (r & 7);
            int ldsoff = (it * 512 + wid * 64) * 16;        // wave-uniform
            gload_lds16(leftT  + (size_t)(bi * 256 + r) * 256 + k0 + s * 8, Abuf[buf] + ldsoff);
            gload_lds16(rightT + (size_t)(bj * 256 + r) * 256 + k0 + s * 8, Bbuf[buf] + ldsoff);
        }
    };

    f32x4 acc[8][4] = {};

    STAGE(0, 0);
    #pragma unroll
    for (int t = 0; t < 4; ++t) {
        if (t < 3) {
            STAGE((t + 1) & 1, (t + 1) * 64);
            asm volatile("s_waitcnt vmcnt(8)" ::: "memory");
        } else {
            asm volatile("s_waitcnt vmcnt(0)" ::: "memory");
        }
        __builtin_amdgcn_s_barrier();
        const __bf16* Al = (const __bf16*)Abuf[t & 1];
        const __bf16* Bl = (const __bf16*)Bbuf[t & 1];
        #pragma unroll
        for (int kk = 0; kk < 2; ++kk) {
            bf16x8 af[8], bfv[4];
            int sb = kk * 4 + lhi;
            #pragma unroll
            for (int fr = 0; fr < 8; ++fr) {
                int row = wr * 128 + fr * 16 + llo;
                af[fr] = *(const bf16x8*)(Al + row * 64 + ((sb ^ (row & 7)) << 3));
            }
            #pragma unroll
            for (int fc = 0; fc < 4; ++fc) {
                int row = wc * 64 + fc * 16 + llo;
                bfv[fc] = *(const bf16x8*)(Bl + row * 64 + ((sb ^ (row & 7)) << 3));
            }
            asm volatile("s_waitcnt lgkmcnt(0)" ::: "memory");
            __builtin_amdgcn_sched_barrier(0);
            __builtin_amdgcn_s_setprio(1);
            #pragma unroll
            for (int fr = 0; fr < 8; ++fr)
                #pragma unroll
                for (int fc = 0; fc < 4; ++fc)
                    acc[fr][fc] = __builtin_amdgcn_mfma_f32_16x16x32_bf16(af[fr], bfv[fc], acc[fr][fc], 0, 0, 0);
            __builtin_amdgcn_s_setprio(0);
            __builtin_amdgcn_s_barrier();      // mid (kk=0) / trailing (kk=1)
        }
    }

    // ---- O-tile -> A_ep[64 ij][1024 cd'] bf16, b64 writes, pi-swizzle ----
    // cd' = d*32+c; ij = (gi>>5)*8 + (gj>>5); t = cd'>>3;
    // phys = ((t&3)<<5 | (t>>2)) ^ (ij&15)   [bijective; 2-way max]
    __bf16* Aep = (__bf16*)smem;
    #pragma unroll
    for (int fr = 0; fr < 8; ++fr) {
        #pragma unroll
        for (int fc = 0; fc < 4; ++fc) {
            int ij = (wr * 4 + (fr >> 1)) * 8 + wc * 2 + (fc >> 1);
            int t = ((fc & 1) * 16 + llo) * 4 + (fr & 1) * 2 + (lhi >> 1);
            int phys = (((t & 3) << 5) | (t >> 2)) ^ (ij & 15);
            bf16x4 v;
            v[0] = (__bf16)acc[fr][fc][0]; v[1] = (__bf16)acc[fr][fc][1];
            v[2] = (__bf16)acc[fr][fc][2]; v[3] = (__bf16)acc[fr][fc][3];
            *(bf16x4*)(Aep + ij * 1024 + (phys << 3) + (lhi & 1) * 4) = v;
        }
    }
    __syncthreads();

    // ---- epilogue GEMM: wave owns p = wid*16+llo, mf = 4 ----
    f32x4 eacc[4] = {};
    const int p = wid * 16 + llo;
    const __bf16* wrow = woT + (size_t)p * 1024 + lhi * 8;
    #pragma unroll 8
    for (int k0 = 0; k0 < 1024; k0 += 32) {
        bf16x8 bw = *(const bf16x8*)(wrow + k0);
        int base = (lhi << 5) | (k0 >> 5);
        #pragma unroll
        for (int mf = 0; mf < 4; ++mf) {
            int ij = mf * 16 + llo;            // ij & 15 == llo
            int phys = base ^ llo;
            bf16x8 a = *(const bf16x8*)(Aep + ij * 1024 + (phys << 3));
            eacc[mf] = __builtin_amdgcn_mfma_f32_16x16x32_bf16(a, bw, eacc[mf], 0, 0, 0);
        }
    }

    const float bov = bo[p];
    #pragma unroll
    for (int mf = 0; mf < 4; ++mf) {
        #pragma unroll
        for (int r = 0; r < 4; ++r) {
            int ij = mf * 16 + lhi * 4 + r;
            int i = bi * 8 + (ij >> 3);
            int j = bj * 8 + (ij & 7);
            size_t idx = (size_t)i * NSEQ + j;
            out[idx * 128 + p] = (eacc[mf][r] + bov) * inv_cnt[idx];
        }
    }
}

// -------------------------------------------------------------- launch ----
extern "C" void kernel_launch(void* const* d_in, const int* in_sizes, int n_in,
                              void* d_out, int out_size, void* d_ws, size_t ws_size,
                              hipStream_t stream) {
    const float* x    = (const float*)d_in[0];
    const int*   mask = (const int*)  d_in[1];
    const float* ln_g = (const float*)d_in[2];
    const float* ln_b = (const float*)d_in[3];
    const float* wl   = (const float*)d_in[4];
    const float* bl   = (const float*)d_in[5];
    const float* wr   = (const float*)d_in[6];
    const float* br   = (const float*)d_in[7];
    const float* wo   = (const float*)d_in[8];
    const float* bo   = (const float*)d_in[9];
    float* out = (float*)d_out;

    char* ws = (char*)d_ws;
    __bf16* leftT   = (__bf16*)(ws);             // 6,291,456
    __bf16* rightT  = (__bf16*)(ws + 6291456);   // 6,291,456
    __bf16* woT     = (__bf16*)(ws + 12582912);  // 262,144
    __bf16* wg      = (__bf16*)(ws + 12845056);  // 32,768
    float*  Gc      = (float*) (ws + 12877824);  // 256
    float*  B2      = (float*) (ws + 12878080);  // 256
    float*  inv_cnt = (float*) (ws + 12878336);  // 589,824 (end ~13.5 MB)

    prep_all_kernel<<<960, 256, 0, stream>>>(wo, wl, wr, bl, br, ln_g, ln_b, mask,
                                             woT, wg, Gc, B2, inv_cnt);
    ln_proj_kernel<<<768, 256, 0, stream>>>(x, mask, wg, Gc, B2, leftT, rightT);
    outer_gemm_kernel<<<2304, 512, 0, stream>>>(leftT, rightT, woT, bo, inv_cnt, out);
}

// Round 15
// 176.927 us; speedup vs baseline: 1.2274x; 1.0610x over previous
//
#include <hip/hip_runtime.h>
#include <hip/hip_bf16.h>
#include <stdint.h>

// OuterProductMean: b=1, m=256 (MSA), n=384 (seq), C=256, H=32, P=128.
//   prep_all: woT[p][cd'] bf16 (cd'=d*32+c); wg/Gc/B2; maskbits pack
//             (col -> 4 x u64 via LDS-staged ballot).
//   ln_proj:  blocks [0,1536): single-pass LN+proj, m-split x4;
//             blocks [1536,1632): cnt via popcount(maskbits) -> inv_cnt.
//   outer:    R14 champion verbatim (256x256 tile, 16x16x32 main loop, dbuf
//             global_load_lds + vmcnt(8), L2-tiled XCD remap, b64 A_ep writes
//             w/ bijective swizzle, p=wid*16+llo epilogue).

typedef float f32x4 __attribute__((ext_vector_type(4)));
typedef __bf16 bf16x8 __attribute__((ext_vector_type(8)));
typedef __bf16 bf16x4 __attribute__((ext_vector_type(4)));

#define NSEQ 384
#define NMSA 256

typedef const __attribute__((address_space(1))) unsigned int* gptr_t;
typedef __attribute__((address_space(3))) unsigned int* lptr_t;

__device__ __forceinline__ void gload_lds16(const void* g, void* l) {
    __builtin_amdgcn_global_load_lds((gptr_t)g, (lptr_t)l, 16, 0, 0);
}

// ------------------------------------------------------------- prep_all ----
// blocks [0,512): woT (cd' reorder); [512,576): wg/Gc/B2; [576,582): pack.
__global__ __launch_bounds__(256) void prep_all_kernel(
    const float* __restrict__ wo,
    const float* __restrict__ wl, const float* __restrict__ wr,
    const float* __restrict__ bl, const float* __restrict__ br,
    const float* __restrict__ ln_g, const float* __restrict__ ln_b,
    const int* __restrict__ mask,
    __bf16* __restrict__ woT, __bf16* __restrict__ wg,
    float* __restrict__ Gc, float* __restrict__ B2,
    unsigned long long* __restrict__ maskbits)
{
    const int blk = blockIdx.x;

    if (blk < 512) {                           // woT[p*1024 + d*32 + c]
        int gid = blk * 256 + threadIdx.x;     // 131072 total
        int p = gid >> 10, q = gid & 1023;
        int d = q >> 5, c = q & 31;
        woT[gid] = (__bf16)wo[(c * 32 + d) * 128 + p];
    } else if (blk < 576) {                    // wg / Gc / B2
        __shared__ float sg[4], sb[4];
        const int c = blk - 512;               // 0..63
        const int k = threadIdx.x;             // 0..255
        float w = (c < 32) ? wl[k * 32 + c] : wr[k * 32 + (c - 32)];
        __bf16 wgb = (__bf16)(w * ln_g[k]);
        wg[c * 256 + k] = wgb;
        float gsum = (float)wgb;               // rounded so mu-term cancels
        float bsum = w * ln_b[k];
        for (int off = 32; off; off >>= 1) {
            gsum += __shfl_down(gsum, off);
            bsum += __shfl_down(bsum, off);
        }
        int wid = k >> 6, lane = k & 63;
        if (lane == 0) { sg[wid] = gsum; sb[wid] = bsum; }
        __syncthreads();
        if (k == 0) {
            Gc[c] = sg[0] + sg[1] + sg[2] + sg[3];
            B2[c] = sb[0] + sb[1] + sb[2] + sb[3] + ((c < 32) ? bl[c] : br[c - 32]);
        }
    } else {                                   // pack: cols [b*64, b*64+64)
        __shared__ int tile[256 * 65];         // pitch 65 -> 2-way on ballot reads
        const int b = blk - 576;               // 0..5
        const int tid = threadIdx.x;
        #pragma unroll
        for (int it = 0; it < 64; ++it) {      // coalesced tile load
            int e = it * 256 + tid;
            int m = e >> 6, c = e & 63;
            tile[m * 65 + c] = mask[m * NSEQ + b * 64 + c];
        }
        __syncthreads();
        const int w = tid >> 6, lane = tid & 63;
        for (int c = 0; c < 64; ++c) {
            unsigned long long bits = __ballot(tile[(w * 64 + lane) * 65 + c] != 0);
            if (lane == 0) maskbits[(size_t)(b * 64 + c) * 4 + w] = bits;
        }
    }
}

// ------------------------------------------------------------- ln_proj ----
// blocks [0,1536): LN+proj for (n = blk%384, m-range [mh*64, mh*64+64));
// blocks [1536,1632): cnt rows i = (blk-1536)*4 + wave.
__global__ __launch_bounds__(256) void ln_proj_kernel(
    const float* __restrict__ x, const int* __restrict__ mask,
    const __bf16* __restrict__ wg, const float* __restrict__ Gc,
    const float* __restrict__ B2,
    const unsigned long long* __restrict__ maskbits,
    __bf16* __restrict__ leftT, __bf16* __restrict__ rightT,
    float* __restrict__ inv_cnt)
{
    const int tid = threadIdx.x;

    if (blockIdx.x >= 1536) {                  // ---- cnt via popcount ----
        const int idx = blockIdx.x - 1536;     // 0..95
        const int w = tid >> 6, lane = tid & 63;
        const int i = idx * 4 + w;             // row 0..383
        unsigned long long bi0 = maskbits[(size_t)i * 4 + 0];
        unsigned long long bi1 = maskbits[(size_t)i * 4 + 1];
        unsigned long long bi2 = maskbits[(size_t)i * 4 + 2];
        unsigned long long bi3 = maskbits[(size_t)i * 4 + 3];
        #pragma unroll
        for (int s = 0; s < 6; ++s) {
            int j = lane + s * 64;
            const unsigned long long* bj = maskbits + (size_t)j * 4;
            int c = __popcll(bi0 & bj[0]) + __popcll(bi1 & bj[1])
                  + __popcll(bi2 & bj[2]) + __popcll(bi3 & bj[3]);
            inv_cnt[i * NSEQ + j] = 1.0f / ((float)c + 0.001f);
        }
        return;
    }

    const int n = blockIdx.x % NSEQ;
    const int mh = blockIdx.x / NSEQ;          // 0..3
    const int m0 = mh * 64;
    __shared__ __bf16 xnT[64 * 40];
    __shared__ float muS[64], rsS[64], maskS[64], GcS[64], B2S[64];

    if (tid < 64) {
        GcS[tid] = Gc[tid]; B2S[tid] = B2[tid];
        maskS[tid] = (float)mask[(m0 + tid) * NSEQ + n];
    }

    const int wid = tid >> 6, lane = tid & 63;
    const int lhi = lane >> 4, llo = lane & 15;
    const int wrq = wid >> 1, wcq = wid & 1;   // 2x2 waves: c-half x m-half(32)
    float ps[2] = {}, pq[2] = {};
    f32x4 acc[2][2] = {};

    for (int k0 = 0; k0 < 256; k0 += 32) {
        #pragma unroll
        for (int cc = 0; cc < 2; ++cc) {       // stage raw x [64 m][32 k] bf16
            int ch = tid + cc * 256;
            int mR = ch >> 3, c4 = ch & 7;
            f32x4 v = *reinterpret_cast<const f32x4*>(x + ((size_t)(m0 + mR) * NSEQ + n) * 256 + k0 + c4 * 4);
            ps[cc] += v[0] + v[1] + v[2] + v[3];
            pq[cc] += v[0]*v[0] + v[1]*v[1] + v[2]*v[2] + v[3]*v[3];
            __bf16* dst = xnT + mR * 40 + c4 * 4;
            dst[0] = (__bf16)v[0]; dst[1] = (__bf16)v[1];
            dst[2] = (__bf16)v[2]; dst[3] = (__bf16)v[3];
        }
        __syncthreads();
        bf16x8 af[2], bfr[2];
        #pragma unroll
        for (int fr = 0; fr < 2; ++fr)
            af[fr] = *reinterpret_cast<const bf16x8*>(wg + (size_t)(wrq * 32 + fr * 16 + llo) * 256 + k0 + lhi * 8);
        #pragma unroll
        for (int fc = 0; fc < 2; ++fc)
            bfr[fc] = *reinterpret_cast<const bf16x8*>(xnT + (wcq * 32 + fc * 16 + llo) * 40 + lhi * 8);
        #pragma unroll
        for (int fr = 0; fr < 2; ++fr)
            #pragma unroll
            for (int fc = 0; fc < 2; ++fc)
                acc[fr][fc] = __builtin_amdgcn_mfma_f32_16x16x32_bf16(af[fr], bfr[fc], acc[fr][fc], 0, 0, 0);
        __syncthreads();
    }

    #pragma unroll
    for (int cc = 0; cc < 2; ++cc) {
        float s = ps[cc], q = pq[cc];
        s += __shfl_xor(s, 1); q += __shfl_xor(q, 1);
        s += __shfl_xor(s, 2); q += __shfl_xor(q, 2);
        s += __shfl_xor(s, 4); q += __shfl_xor(q, 4);
        if ((tid & 7) == 0) {
            int mR = (tid >> 3) + cc * 32;
            float mu = s * (1.f / 256.f);
            float var = q * (1.f / 256.f) - mu * mu;
            muS[mR] = mu;
            rsS[mR] = rsqrtf(var + 1e-5f);
        }
    }
    __syncthreads();

    #pragma unroll
    for (int fr = 0; fr < 2; ++fr) {
        #pragma unroll
        for (int fc = 0; fc < 2; ++fc) {
            int mR = wcq * 32 + fc * 16 + llo;
            float mv = maskS[mR], rs = rsS[mR], mu = muS[mR];
            #pragma unroll
            for (int r = 0; r < 4; ++r) {
                int c = wrq * 32 + fr * 16 + lhi * 4 + r;
                float val = (acc[fr][fc][r] - mu * GcS[c]) * rs + B2S[c];
                __bf16 bv = (__bf16)(val * mv);
                if (c < 32) leftT [(size_t)(n * 32 + c)        * 256 + m0 + mR] = bv;
                else        rightT[(size_t)(n * 32 + (c - 32)) * 256 + m0 + mR] = bv;
            }
        }
    }
}

// --------------------------------------------------------------- outer ----
// R14 champion verbatim (L2-tiled XCD remap).
__global__ __launch_bounds__(512, 2) void outer_gemm_kernel(
    const __bf16* __restrict__ leftT, const __bf16* __restrict__ rightT,
    const __bf16* __restrict__ woT, const float* __restrict__ bo,
    const float* __restrict__ inv_cnt, float* __restrict__ out)
{
    __shared__ char smem[131072];
    const int tid = threadIdx.x;
    const int wid = tid >> 6, lane = tid & 63;
    const int lhi = lane >> 4, llo = lane & 15;
    const int wr = wid >> 2, wc = wid & 3;     // 2x4 wave grid, wave = 128x64

    // L2-tiled XCD remap: XCD owns bj in [xcd*6, xcd*6+6); blocks ordered as
    // {bi-group of 8} x {6 bj} x {8 bi} -> ~1.8MB working set < 4MB L2.
    int wg_ = blockIdx.x;
    int xcd = wg_ & 7;
    int g   = wg_ >> 3;                        // 0..287
    int big = g / 48;                          // 0..5
    int rem = g - big * 48;
    int bjx = rem >> 3;                        // 0..5
    int bii = rem & 7;                         // 0..7
    int bi  = big * 8 + bii;                   // 0..47
    int bj  = xcd * 6 + bjx;                   // 0..47

    char* Abuf[2] = { smem,         smem + 65536 };
    char* Bbuf[2] = { smem + 32768, smem + 98304 };

    auto STAGE = [&](int buf, int k0) {
        #pragma unroll
        for (int it = 0; it < 4; ++it) {
            int q = it * 512 + wid * 64 + lane;
            int r = q >> 3;
            int s = (q & 7) ^ (r & 7);
            int ldsoff = (it * 512 + wid * 64) * 16;        // wave-uniform
            gload_lds16(leftT  + (size_t)(bi * 256 + r) * 256 + k0 + s * 8, Abuf[buf] + ldsoff);
            gload_lds16(rightT + (size_t)(bj * 256 + r) * 256 + k0 + s * 8, Bbuf[buf] + ldsoff);
        }
    };

    f32x4 acc[8][4] = {};

    STAGE(0, 0);
    #pragma unroll
    for (int t = 0; t < 4; ++t) {
        if (t < 3) {
            STAGE((t + 1) & 1, (t + 1) * 64);
            asm volatile("s_waitcnt vmcnt(8)" ::: "memory");
        } else {
            asm volatile("s_waitcnt vmcnt(0)" ::: "memory");
        }
        __builtin_amdgcn_s_barrier();
        const __bf16* Al = (const __bf16*)Abuf[t & 1];
        const __bf16* Bl = (const __bf16*)Bbuf[t & 1];
        #pragma unroll
        for (int kk = 0; kk < 2; ++kk) {
            bf16x8 af[8], bfv[4];
            int sb = kk * 4 + lhi;
            #pragma unroll
            for (int fr = 0; fr < 8; ++fr) {
                int row = wr * 128 + fr * 16 + llo;
                af[fr] = *(const bf16x8*)(Al + row * 64 + ((sb ^ (row & 7)) << 3));
            }
            #pragma unroll
            for (int fc = 0; fc < 4; ++fc) {
                int row = wc * 64 + fc * 16 + llo;
                bfv[fc] = *(const bf16x8*)(Bl + row * 64 + ((sb ^ (row & 7)) << 3));
            }
            asm volatile("s_waitcnt lgkmcnt(0)" ::: "memory");
            __builtin_amdgcn_sched_barrier(0);
            __builtin_amdgcn_s_setprio(1);
            #pragma unroll
            for (int fr = 0; fr < 8; ++fr)
                #pragma unroll
                for (int fc = 0; fc < 4; ++fc)
                    acc[fr][fc] = __builtin_amdgcn_mfma_f32_16x16x32_bf16(af[fr], bfv[fc], acc[fr][fc], 0, 0, 0);
            __builtin_amdgcn_s_setprio(0);
            __builtin_amdgcn_s_barrier();      // mid (kk=0) / trailing (kk=1)
        }
    }

    // ---- O-tile -> A_ep[64 ij][1024 cd'] bf16, b64 writes, pi-swizzle ----
    __bf16* Aep = (__bf16*)smem;
    #pragma unroll
    for (int fr = 0; fr < 8; ++fr) {
        #pragma unroll
        for (int fc = 0; fc < 4; ++fc) {
            int ij = (wr * 4 + (fr >> 1)) * 8 + wc * 2 + (fc >> 1);
            int t = ((fc & 1) * 16 + llo) * 4 + (fr & 1) * 2 + (lhi >> 1);
            int phys = (((t & 3) << 5) | (t >> 2)) ^ (ij & 15);
            bf16x4 v;
            v[0] = (__bf16)acc[fr][fc][0]; v[1] = (__bf16)acc[fr][fc][1];
            v[2] = (__bf16)acc[fr][fc][2]; v[3] = (__bf16)acc[fr][fc][3];
            *(bf16x4*)(Aep + ij * 1024 + (phys << 3) + (lhi & 1) * 4) = v;
        }
    }
    __syncthreads();

    // ---- epilogue GEMM: wave owns p = wid*16+llo, mf = 4 ----
    f32x4 eacc[4] = {};
    const int p = wid * 16 + llo;
    const __bf16* wrow = woT + (size_t)p * 1024 + lhi * 8;
    #pragma unroll 8
    for (int k0 = 0; k0 < 1024; k0 += 32) {
        bf16x8 bw = *(const bf16x8*)(wrow + k0);
        int base = (lhi << 5) | (k0 >> 5);
        #pragma unroll
        for (int mf = 0; mf < 4; ++mf) {
            int ij = mf * 16 + llo;            // ij & 15 == llo
            int phys = base ^ llo;
            bf16x8 a = *(const bf16x8*)(Aep + ij * 1024 + (phys << 3));
            eacc[mf] = __builtin_amdgcn_mfma_f32_16x16x32_bf16(a, bw, eacc[mf], 0, 0, 0);
        }
    }

    const float bov = bo[p];
    #pragma unroll
    for (int mf = 0; mf < 4; ++mf) {
        #pragma unroll
        for (int r = 0; r < 4; ++r) {
            int ij = mf * 16 + lhi * 4 + r;
            int i = bi * 8 + (ij >> 3);
            int j = bj * 8 + (ij & 7);
            size_t idx = (size_t)i * NSEQ + j;
            out[idx * 128 + p] = (eacc[mf][r] + bov) * inv_cnt[idx];
        }
    }
}

// -------------------------------------------------------------- launch ----
extern "C" void kernel_launch(void* const* d_in, const int* in_sizes, int n_in,
                              void* d_out, int out_size, void* d_ws, size_t ws_size,
                              hipStream_t stream) {
    const float* x    = (const float*)d_in[0];
    const int*   mask = (const int*)  d_in[1];
    const float* ln_g = (const float*)d_in[2];
    const float* ln_b = (const float*)d_in[3];
    const float* wl   = (const float*)d_in[4];
    const float* bl   = (const float*)d_in[5];
    const float* wr   = (const float*)d_in[6];
    const float* br   = (const float*)d_in[7];
    const float* wo   = (const float*)d_in[8];
    const float* bo   = (const float*)d_in[9];
    float* out = (float*)d_out;

    char* ws = (char*)d_ws;
    __bf16* leftT   = (__bf16*)(ws);             // 6,291,456
    __bf16* rightT  = (__bf16*)(ws + 6291456);   // 6,291,456
    __bf16* woT     = (__bf16*)(ws + 12582912);  // 262,144
    __bf16* wg      = (__bf16*)(ws + 12845056);  // 32,768
    float*  Gc      = (float*) (ws + 12877824);  // 256
    float*  B2      = (float*) (ws + 12878080);  // 256
    float*  inv_cnt = (float*) (ws + 12878336);  // 589,824
    unsigned long long* maskbits = (unsigned long long*)(ws + 13468160); // 12,288

    prep_all_kernel<<<582, 256, 0, stream>>>(wo, wl, wr, bl, br, ln_g, ln_b, mask,
                                             woT, wg, Gc, B2, maskbits);
    ln_proj_kernel<<<1632, 256, 0, stream>>>(x, mask, wg, Gc, B2, maskbits,
                                             leftT, rightT, inv_cnt);
    outer_gemm_kernel<<<2304, 512, 0, stream>>>(leftT, rightT, woT, bo, inv_cnt, out);
}